// Round 16
// baseline (244.699 us; speedup 1.0000x reference)
//
#include <hip/hip_runtime.h>
#include <hip/hip_bf16.h>

// VQ-VAE vector quantizer, MI355X. z:(16,512,64,64) f32, codebook:(1024,512) f32.
// d_out f32: z_q (33554432), loss (1), idx (65536).
// R16: K-split wave pairs (kh=0/1 each 256 ch) -> bfrag 64 VGPR -> 3 waves/SIMD.
// 1024 blocks x 256 thr (4 waves = 2 pxg x 2 kh), 64 px/block, full codebook.
// 8KB stages (32 codes x 128 ch), 3-ring, counted vmcnt(2), LDS acc exchange.

typedef _Float16 h8 __attribute__((ext_vector_type(8)));
typedef float f32x16 __attribute__((ext_vector_type(16)));

#define OUT_LOSS  33554432
#define OUT_IDX   33554433
#define MARGIN_T  0.15f

__device__ __forceinline__ void gload_lds16(const void* g, void* l) {
  __builtin_amdgcn_global_load_lds(
      (const __attribute__((address_space(1))) void*)g,
      (__attribute__((address_space(3))) void*)l, 16, 0, 0);
}

__device__ __forceinline__ int zswz(int row) {
  return ((row & 3) << 6) | (((row >> 2) & 3) << 4);
}

// ---- K0: cb fp32 -> fp16 cbT with 8KB-stage layout + cnorm + ws init ---------
// stage st = c*4+sub: codes c*32..+32, ch sub*128..+128. Within stage: slot s
// (16 ch), entry (hk*32+rr)*16B. dst = st*8192 + s*1024 + (hk*32+rr)*16.
__global__ __launch_bounds__(64) void k0_prep(
    const float* __restrict__ cb, unsigned short* __restrict__ cbT,
    float* __restrict__ cnp, int* __restrict__ counters, float* __restrict__ loss_acc,
    int* __restrict__ idx_ws, unsigned long long* __restrict__ packed_ws)
{
  const int r = blockIdx.x, l = threadIdx.x;   // r: code row, l: 8-ch group
  const float* row = cb + (size_t)r * 512;
  float4 a  = *(const float4*)(row + l * 8);
  float4 b4 = *(const float4*)(row + l * 8 + 4);
  h8 hv;
  hv[0] = (_Float16)a.x;  hv[1] = (_Float16)a.y;  hv[2] = (_Float16)a.z;  hv[3] = (_Float16)a.w;
  hv[4] = (_Float16)b4.x; hv[5] = (_Float16)b4.y; hv[6] = (_Float16)b4.z; hv[7] = (_Float16)b4.w;
  {
    const int c   = r >> 5, rr = r & 31;
    const int sub = l >> 4;              // 128-ch sub-stage
    const int s   = (l >> 1) & 7;        // 16-ch slot within sub
    const int hk  = l & 1;               // 8-ch half within slot
    char* dst = reinterpret_cast<char*>(cbT)
              + (size_t)(c * 4 + sub) * 8192 + s * 1024 + (hk * 32 + rr) * 16;
    *reinterpret_cast<h8*>(dst) = hv;
  }
  float s = a.x*a.x + a.y*a.y + a.z*a.z + a.w*a.w
          + b4.x*b4.x + b4.y*b4.y + b4.z*b4.z + b4.w*b4.w;
  #pragma unroll
  for (int off = 1; off < 64; off <<= 1) s += __shfl_xor(s, off);
  if (l == 0) {
    int jr = r & 31, c = r >> 5;
    int khalf = (jr >> 2) & 1;
    int pat = jr - (khalf << 2);
    int rr2 = (pat & 3) + ((pat >> 3) << 2);
    cnp[(c << 5) + (khalf << 4) + rr2] = 0.5f * s;
  }
  const int pix = (r << 6) + l;
  idx_ws[pix] = (int)0x80000000;
  packed_ws[pix] = ~0ull;
  if (r == 0 && l < 4) counters[l] = 0;
  if (r == 0 && l == 0) *loss_acc = 0.f;
}

// ---- K1: K-split MFMA scan ----------------------------------------------------
// LDS: [0,24576) 3x8KB ring | [24576,40960) exch 2x8KB (also z-tile at prologue)
//      [40960,45056) cnorm. dynLDS = 45056.
__global__ __launch_bounds__(256, 3) void k1_main(
    const float* __restrict__ z, const unsigned short* __restrict__ cbT,
    const float* __restrict__ cnp,
    int* __restrict__ idx_ws, int* __restrict__ flaglist,
    unsigned long long* __restrict__ pairlist, int* __restrict__ counters)
{
  extern __shared__ char smem[];
  char*  exch   = smem + 24576;
  float* cn_lds = reinterpret_cast<float*>(smem + 40960);
  const int tid   = threadIdx.x;
  const int lane  = tid & 63;
  const int wave  = tid >> 6;          // 0..3
  const int pxg   = wave & 1;          // pixel subgroup (32 px)
  const int kh    = wave >> 1;         // channel half: 0 -> ch[0,256), 1 -> [256,512)
  const int pxl   = lane & 31;
  const int khalf = lane >> 5;         // mfma-internal split (codes / 8-ch)
  const int px0   = blockIdx.x << 6;   // 64 px/block
  const int b     = px0 >> 12;
  const int hw0   = px0 & 4095;
  const char* cbB = reinterpret_cast<const char*>(cbT);

  // issue cb stage 0,1 immediately (land during z prologue)
  #pragma unroll
  for (int i = 0; i < 2; ++i)
    gload_lds16(cbB + tid * 16 + i * 4096, smem + tid * 16 + i * 4096);
  #pragma unroll
  for (int i = 0; i < 2; ++i)
    gload_lds16(cbB + 8192 + tid * 16 + i * 4096, smem + 8192 + tid * 16 + i * 4096);

  // ---- z prologue: 4 passes of [64 px][128 ch] fp16 tile at exch (16 KB) ----
  h8 bfrag[16];     // this wave's 256 channels: 16 slots
  for (int i = tid; i < 1024; i += 256) cn_lds[i] = cnp[i];
  #pragma unroll
  for (int p = 0; p < 4; ++p) {
    {
      const int cg  = tid >> 4;                  // 0..15
      const int ch0 = cg * 8;                    // 0..120 within pass
      const int pq  = (tid & 15) * 4;            // 0..60
      const float* src = z + ((size_t)(b * 512 + p * 128 + ch0)) * 4096 + hw0 + pq;
      float4 v[8];
      #pragma unroll
      for (int j = 0; j < 8; ++j) v[j] = *(const float4*)(src + (size_t)j * 4096);
      const float* vf = reinterpret_cast<const float*>(v);
      #pragma unroll
      for (int dp = 0; dp < 4; ++dp) {
        h8 hv;
        #pragma unroll
        for (int j = 0; j < 8; ++j) hv[j] = (_Float16)vf[j * 4 + dp];
        int row = pq + dp;                       // 0..63
        int a = ((row << 8) + ch0 * 2) ^ zswz(row);
        *reinterpret_cast<h8*>(exch + a) = hv;
      }
    }
    __syncthreads();
    if ((p >> 1) == kh) {
      const int row  = (pxg << 5) + pxl;
      const int sw   = zswz(row);
      const int base = (row << 8) + (khalf << 4);
      #pragma unroll
      for (int ss = 0; ss < 8; ++ss)
        bfrag[(p & 1) * 8 + ss] =
            *reinterpret_cast<const h8*>(exch + ((base + (ss << 5)) ^ sw));
    }
    __syncthreads();
  }
  // NOTE: __syncthreads above drained vmcnt to 0 (stage 0,1 landed long ago).

  float v0 = INFINITY, v1 = INFINITY, v2 = INFINITY, v3 = INFINITY;
  int   i0 = 0, i1 = 0, i2 = 0, i3 = 0;
  f32x16 acca, accb;
  #pragma unroll
  for (int i = 0; i < 16; ++i) { acca[i] = 0.f; accb[i] = 0.f; }

  char* p0 = smem;            // ring: current stage
  char* p1 = smem + 8192;
  char* p2 = smem + 16384;
  const bool mine0 = (kh == 0), mine1 = (kh == 1);

  for (int c = 0; c < 32; ++c) {
    const int stb = c << 2;
    #pragma unroll
    for (int sub = 0; sub < 4; ++sub) {
      const int st = stb + sub;
      if (st != 127) { asm volatile("s_waitcnt vmcnt(2)" ::: "memory"); }
      else           { asm volatile("s_waitcnt vmcnt(0)" ::: "memory"); }
      __builtin_amdgcn_s_barrier();
      __builtin_amdgcn_sched_barrier(0);

      // fold chunk c-1 (kh0 waves) at the first sub of each chunk
      if (sub == 0 && c > 0 && kh == 0) {
        const float* exb = reinterpret_cast<const float*>(
            exch + (((c - 1) & 1) << 13) + (pxg << 12) + lane * 64);
        float4 e0 = *(const float4*)(exb);
        float4 e1 = *(const float4*)(exb + 4);
        float4 e2 = *(const float4*)(exb + 8);
        float4 e3 = *(const float4*)(exb + 12);
        const float ex[16] = {e0.x,e0.y,e0.z,e0.w, e1.x,e1.y,e1.z,e1.w,
                              e2.x,e2.y,e2.z,e2.w, e3.x,e3.y,e3.z,e3.w};
        const int cc = c - 1;
        const float* cl = cn_lds + (cc << 5) + (khalf << 4);
        float4 q0 = *(const float4*)(cl);     float4 q1 = *(const float4*)(cl + 4);
        float4 q2 = *(const float4*)(cl + 8); float4 q3 = *(const float4*)(cl + 12);
        const float cn[16] = {q0.x,q0.y,q0.z,q0.w, q1.x,q1.y,q1.z,q1.w,
                              q2.x,q2.y,q2.z,q2.w, q3.x,q3.y,q3.z,q3.w};
        float sc[16];
        #pragma unroll
        for (int r = 0; r < 16; ++r) sc[r] = cn[r] - (acca[r] + accb[r] + ex[r]);
        float mn = sc[0];
        #pragma unroll
        for (int r = 1; r < 16; ++r) mn = fminf(mn, sc[r]);
        if (__ballot(mn < v3)) {
          const int jbase = (cc << 5) + (khalf << 2);
          #pragma unroll
          for (int r = 0; r < 16; ++r) {
            int j = jbase + ((r & 3) + ((r >> 2) << 3));
            float s = sc[r];
            bool c0 = s < v0, c1 = s < v1, c2 = s < v2, c3 = s < v3;
            v3 = c2 ? v2 : (c3 ? s : v3);  i3 = c2 ? i2 : (c3 ? j : i3);
            v2 = c1 ? v1 : (c2 ? s : v2);  i2 = c1 ? i1 : (c2 ? j : i2);
            v1 = c0 ? v0 : (c1 ? s : v1);  i1 = c0 ? i0 : (c1 ? j : i1);
            v0 = c0 ? s  : v0;             i0 = c0 ? j  : i0;
          }
        }
        #pragma unroll
        for (int i = 0; i < 16; ++i) { acca[i] = 0.f; accb[i] = 0.f; }
      }

      if (st + 2 < 128) {   // stage st+2 -> p2 (read at st-1... rotated ring)
        const char* src = cbB + (size_t)(st + 2) * 8192 + tid * 16;
        gload_lds16(src,        p2 + tid * 16);
        gload_lds16(src + 4096, p2 + tid * 16 + 4096);
      }

      const bool mine = (sub < 2) ? mine0 : mine1;
      if (mine) {
        const char* ab = p0 + (khalf << 9) + (pxl << 4);
        h8 f[8];
        #pragma unroll
        for (int q = 0; q < 8; ++q) f[q] = *reinterpret_cast<const h8*>(ab + (q << 10));
        __builtin_amdgcn_s_setprio(1);
        #pragma unroll
        for (int q = 0; q < 4; ++q) {
          acca = __builtin_amdgcn_mfma_f32_32x32x16_f16(f[q],     bfrag[(sub & 1) * 8 + q],     acca, 0, 0, 0);
          accb = __builtin_amdgcn_mfma_f32_32x32x16_f16(f[q + 4], bfrag[(sub & 1) * 8 + q + 4], accb, 0, 0, 0);
        }
        __builtin_amdgcn_s_setprio(0);
      }

      // end of chunk: kh1 publishes its partial acc
      if (sub == 3 && kh == 1) {
        float* exw = reinterpret_cast<float*>(
            exch + ((c & 1) << 13) + (pxg << 12) + lane * 64);
        float4 w0, w1, w2, w3;
        w0.x = acca[0]  + accb[0];  w0.y = acca[1]  + accb[1];
        w0.z = acca[2]  + accb[2];  w0.w = acca[3]  + accb[3];
        w1.x = acca[4]  + accb[4];  w1.y = acca[5]  + accb[5];
        w1.z = acca[6]  + accb[6];  w1.w = acca[7]  + accb[7];
        w2.x = acca[8]  + accb[8];  w2.y = acca[9]  + accb[9];
        w2.z = acca[10] + accb[10]; w2.w = acca[11] + accb[11];
        w3.x = acca[12] + accb[12]; w3.y = acca[13] + accb[13];
        w3.z = acca[14] + accb[14]; w3.w = acca[15] + accb[15];
        *(float4*)(exw)      = w0;  *(float4*)(exw + 4)  = w1;
        *(float4*)(exw + 8)  = w2;  *(float4*)(exw + 12) = w3;
        asm volatile("s_waitcnt lgkmcnt(0)" ::: "memory");
        #pragma unroll
        for (int i = 0; i < 16; ++i) { acca[i] = 0.f; accb[i] = 0.f; }
      }

      { char* t = p0; p0 = p1; p1 = p2; p2 = t; }
    }
  }

  // final chunk (c=31) fold
  __builtin_amdgcn_s_barrier();
  if (kh == 0) {
    const float* exb = reinterpret_cast<const float*>(
        exch + ((31 & 1) << 13) + (pxg << 12) + lane * 64);
    float4 e0 = *(const float4*)(exb);
    float4 e1 = *(const float4*)(exb + 4);
    float4 e2 = *(const float4*)(exb + 8);
    float4 e3 = *(const float4*)(exb + 12);
    const float ex[16] = {e0.x,e0.y,e0.z,e0.w, e1.x,e1.y,e1.z,e1.w,
                          e2.x,e2.y,e2.z,e2.w, e3.x,e3.y,e3.z,e3.w};
    const float* cl = cn_lds + (31 << 5) + (khalf << 4);
    float4 q0 = *(const float4*)(cl);     float4 q1 = *(const float4*)(cl + 4);
    float4 q2 = *(const float4*)(cl + 8); float4 q3 = *(const float4*)(cl + 12);
    const float cn[16] = {q0.x,q0.y,q0.z,q0.w, q1.x,q1.y,q1.z,q1.w,
                          q2.x,q2.y,q2.z,q2.w, q3.x,q3.y,q3.z,q3.w};
    float sc[16];
    #pragma unroll
    for (int r = 0; r < 16; ++r) sc[r] = cn[r] - (acca[r] + accb[r] + ex[r]);
    float mn = sc[0];
    #pragma unroll
    for (int r = 1; r < 16; ++r) mn = fminf(mn, sc[r]);
    if (__ballot(mn < v3)) {
      const int jbase = (31 << 5) + (khalf << 2);
      #pragma unroll
      for (int r = 0; r < 16; ++r) {
        int j = jbase + ((r & 3) + ((r >> 2) << 3));
        float s = sc[r];
        bool c0 = s < v0, c1 = s < v1, c2 = s < v2, c3 = s < v3;
        v3 = c2 ? v2 : (c3 ? s : v3);  i3 = c2 ? i2 : (c3 ? j : i3);
        v2 = c1 ? v1 : (c2 ? s : v2);  i2 = c1 ? i1 : (c2 ? j : i2);
        v1 = c0 ? v0 : (c1 ? s : v1);  i1 = c0 ? i0 : (c1 ? j : i1);
        v0 = c0 ? s  : v0;             i0 = c0 ? j  : i0;
      }
    }

    // merge khalf code-subsets: snapshot partner BEFORE mutating
    {
      float ow0 = __shfl_xor(v0, 32), ow1 = __shfl_xor(v1, 32),
            ow2 = __shfl_xor(v2, 32), ow3 = __shfl_xor(v3, 32);
      int   oj0 = __shfl_xor(i0, 32), oj1 = __shfl_xor(i1, 32),
            oj2 = __shfl_xor(i2, 32), oj3 = __shfl_xor(i3, 32);
      const float ow[4] = {ow0, ow1, ow2, ow3};
      const int   oj[4] = {oj0, oj1, oj2, oj3};
      #pragma unroll
      for (int k = 0; k < 4; ++k) {
        float ov = ow[k]; int oi = oj[k];
        bool c0 = ov < v0, c1 = ov < v1, c2 = ov < v2, c3 = ov < v3;
        v3 = c2 ? v2 : (c3 ? ov : v3);  i3 = c2 ? i2 : (c3 ? oi : i3);
        v2 = c1 ? v1 : (c2 ? ov : v2);  i2 = c1 ? i1 : (c2 ? oi : i2);
        v1 = c0 ? v0 : (c1 ? ov : v1);  i1 = c0 ? i0 : (c1 ? oi : i1);
        v0 = c0 ? ov : v0;              i0 = c0 ? oi : i0;
      }
    }

    const int pix = px0 + (pxg << 5) + lane;   // valid for lane<32
    bool sane = (v0 == v0) && (v3 == v3) && ((unsigned)i0 < 1024u);
    bool unfl = sane && (v1 - v0 >= MARGIN_T);
    bool quad = sane && !unfl && (v3 - v0 >= MARGIN_T);
    bool qpred = (lane < 32) && quad;
    bool fpred = (lane < 32) && !unfl && !quad;
    if (lane < 32) idx_ws[pix] = unfl ? i0 : (int)0x80000000;

    unsigned long long qm = __ballot(qpred);
    if (qm) {
      int leader = __ffsll(qm) - 1;
      int base = 0;
      if (lane == leader) base = atomicAdd(&counters[1], __popcll(qm));
      base = __shfl(base, leader);
      if (qpred) {
        int pos = __popcll(qm & ((1ull << lane) - 1ull));
        pairlist[base + pos] = (unsigned long long)(unsigned)pix
            | ((unsigned long long)(unsigned)i0 << 16)
            | ((unsigned long long)(unsigned)i1 << 26)
            | ((unsigned long long)(unsigned)i2 << 36)
            | ((unsigned long long)(unsigned)i3 << 46);
      }
    }
    unsigned long long fm = __ballot(fpred);
    if (fm) {
      int leader = __ffsll(fm) - 1;
      int base = 0;
      if (lane == leader) base = atomicAdd(&counters[0], __popcll(fm));
      base = __shfl(base, leader);
      if (fpred) {
        int pos = __popcll(fm & ((1ull << lane) - 1ull));
        flaglist[base + pos] = pix;
      }
    }
  }
}

// ---- K2a: exact fp64 check of <=4 candidates, one wave per pixel --------------
__global__ __launch_bounds__(256) void k2a_quad(
    const float* __restrict__ z, const float* __restrict__ cb,
    const unsigned long long* __restrict__ pairlist, const int* __restrict__ counters,
    int* __restrict__ idx_ws)
{
  const int lane = threadIdx.x & 63;
  const int wid  = (blockIdx.x << 2) + (threadIdx.x >> 6);
  const int nwav = gridDim.x << 2;
  const int nf   = counters[1];
  for (int e = wid; e < nf; e += nwav) {
    unsigned long long pk = pairlist[e];
    int pix = (int)(pk & 0xFFFFull);
    int c0 = (int)((pk >> 16) & 1023ull), c1 = (int)((pk >> 26) & 1023ull);
    int c2 = (int)((pk >> 36) & 1023ull), c3 = (int)((pk >> 46) & 1023ull);
    const float* zp = z + (size_t)(pix >> 12) * 512 * 4096 + (pix & 4095);
    double s0 = 0, s1 = 0, s2 = 0, s3 = 0;
    #pragma unroll
    for (int k = 0; k < 8; ++k) {
      int c = lane + (k << 6);
      double zv2 = 2.0 * (double)zp[(size_t)c * 4096];
      double a;
      a = (double)cb[(size_t)c0 * 512 + c]; s0 = fma(a, a - zv2, s0);
      a = (double)cb[(size_t)c1 * 512 + c]; s1 = fma(a, a - zv2, s1);
      a = (double)cb[(size_t)c2 * 512 + c]; s2 = fma(a, a - zv2, s2);
      a = (double)cb[(size_t)c3 * 512 + c]; s3 = fma(a, a - zv2, s3);
    }
    #pragma unroll
    for (int off = 32; off > 0; off >>= 1) {
      s0 += __shfl_xor(s0, off); s1 += __shfl_xor(s1, off);
      s2 += __shfl_xor(s2, off); s3 += __shfl_xor(s3, off);
    }
    double bv = s0; int bi = c0;
    if (s1 < bv || (s1 == bv && c1 < bi)) { bv = s1; bi = c1; }
    if (s2 < bv || (s2 == bv && c2 < bi)) { bv = s2; bi = c2; }
    if (s3 < bv || (s3 == bv && c3 < bi)) { bv = s3; bi = c3; }
    if (lane == 0) idx_ws[pix] = bi;
  }
}

// ---- K2b: exact fp64 full re-rank (rare) ---------------------------------------
__global__ __launch_bounds__(256) void k2_rescan(
    const float* __restrict__ z, const float* __restrict__ cb,
    const int* __restrict__ flaglist, const int* __restrict__ counters,
    unsigned long long* __restrict__ packed_ws)
{
  __shared__ float zb[16][512];
  __shared__ unsigned long long best[16];
  __shared__ int pixl[16];
  const int t = threadIdx.x;
  const int nflag = counters[0];
  const int ntasks = ((nflag + 15) >> 4) << 2;
  for (int task = blockIdx.x; task < ntasks; task += gridDim.x) {
    const int g = task >> 2, q = task & 3;
    int rem = nflag - (g << 4);
    const int npx = rem < 16 ? rem : 16;
    if (t < 16) {
      best[t] = ~0ull;
      pixl[t] = (t < npx) ? flaglist[(g << 4) + t] : 0;
    }
    __syncthreads();
    for (int i = t; i < (npx << 9); i += 256) {
      int p = i >> 9, c = i & 511;
      int pix = pixl[p];
      zb[p][c] = z[((size_t)(pix >> 12) * 512 + c) * 4096 + (pix & 4095)];
    }
    __syncthreads();
    const int j = (q << 8) + t;
    const float* row = cb + (size_t)j * 512;
    double dot[16];
    #pragma unroll
    for (int p = 0; p < 16; ++p) dot[p] = 0.0;
    double cn = 0.0;
    for (int k = 0; k < 512; k += 4) {
      float4 cv = *(const float4*)(row + k);
      double c0 = cv.x, c1 = cv.y, c2 = cv.z, c3 = cv.w;
      cn = fma(c0, c0, cn); cn = fma(c1, c1, cn);
      cn = fma(c2, c2, cn); cn = fma(c3, c3, cn);
      #pragma unroll
      for (int p = 0; p < 16; ++p) {
        dot[p] = fma(c0, (double)zb[p][k + 0], dot[p]);
        dot[p] = fma(c1, (double)zb[p][k + 1], dot[p]);
        dot[p] = fma(c2, (double)zb[p][k + 2], dot[p]);
        dot[p] = fma(c3, (double)zb[p][k + 3], dot[p]);
      }
    }
    #pragma unroll
    for (int p = 0; p < 16; ++p) {
      if (p < npx) {
        double d = fma(-2.0, dot[p], cn);
        unsigned long long u = (unsigned long long)__double_as_longlong(d);
        u = (u >> 63) ? ~u : (u | 0x8000000000000000ull);
        unsigned long long pkk = (u & ~1023ull) | (unsigned long long)j;
        atomicMin(&best[p], pkk);
      }
    }
    __syncthreads();
    if (t < npx) atomicMin(&packed_ws[pixl[t]], best[t]);
    __syncthreads();
  }
}

// ---- K3: gather + transpose-write z_q (f32), idx (f32), loss ------------------
__global__ __launch_bounds__(256) void k3_out(
    const float* __restrict__ z, const float* __restrict__ cb,
    const int* __restrict__ idx_ws, const unsigned long long* __restrict__ packed_ws,
    float* __restrict__ out, float* __restrict__ loss_acc)
{
  extern __shared__ float rows[];
  __shared__ int idxs[32];
  __shared__ float wsum[4];
  const int t = threadIdx.x;
  const int pix0 = blockIdx.x << 5;
  const int b = pix0 >> 12, hw0 = pix0 & 4095;
  if (t < 32) {
    int pix = pix0 + t;
    int v = idx_ws[pix];
    unsigned j = (v < 0) ? (unsigned)(packed_ws[pix] & 1023ull) : (unsigned)v;
    j &= 1023u;
    idxs[t] = (int)j;
    out[OUT_IDX + pix] = (float)j;
  }
  __syncthreads();
  for (int i = t; i < 32 * 128; i += 256) {
    int r = i >> 7, kq = (i & 127) << 2;
    float4 v = *(const float4*)(cb + (size_t)idxs[r] * 512 + kq);
    float* dst = rows + r * 513 + kq;
    dst[0] = v.x; dst[1] = v.y; dst[2] = v.z; dst[3] = v.w;
  }
  __syncthreads();
  const int pl = (t & 7) << 2;
  const int cg = t >> 3;
  float acc = 0.f;
  for (int c0 = 0; c0 < 512; c0 += 32) {
    int c = c0 + cg;
    size_t go = ((size_t)(b * 512 + c)) * 4096 + hw0 + pl;
    float4 zv = *(const float4*)(z + go);
    float q0 = rows[(pl + 0) * 513 + c], q1 = rows[(pl + 1) * 513 + c];
    float q2 = rows[(pl + 2) * 513 + c], q3 = rows[(pl + 3) * 513 + c];
    float d0 = q0 - zv.x, d1 = q1 - zv.y, d2 = q2 - zv.z, d3 = q3 - zv.w;
    acc = fmaf(d0, d0, acc); acc = fmaf(d1, d1, acc);
    acc = fmaf(d2, d2, acc); acc = fmaf(d3, d3, acc);
    float4 qv;
    qv.x = zv.x + d0; qv.y = zv.y + d1;
    qv.z = zv.z + d2; qv.w = zv.w + d3;
    *reinterpret_cast<float4*>(out + go) = qv;
  }
  #pragma unroll
  for (int off = 32; off > 0; off >>= 1) acc += __shfl_down(acc, off);
  if ((t & 63) == 0) wsum[t >> 6] = acc;
  __syncthreads();
  if (t == 0) atomicAdd(loss_acc, wsum[0] + wsum[1] + wsum[2] + wsum[3]);
}

__global__ void k4_loss(const float* __restrict__ loss_acc, float* __restrict__ out)
{
  if (threadIdx.x == 0 && blockIdx.x == 0)
    out[OUT_LOSS] = loss_acc[0] * (1.25f / 33554432.f);
}

// ---- launch --------------------------------------------------------------------
extern "C" void kernel_launch(void* const* d_in, const int* in_sizes, int n_in,
                              void* d_out, int out_size, void* d_ws, size_t ws_size,
                              hipStream_t stream) {
  const float* z  = (const float*)d_in[0];
  const float* cb = (const float*)d_in[1];
  float* out = (float*)d_out;
  char* ws = (char*)d_ws;
  unsigned short*      cbT       = (unsigned short*)(ws);                 // 1 MB
  float*               cnp       = (float*)(ws + 1048576);                // 4 KB
  int*                 idx_ws    = (int*)(ws + 1052672);                  // 256 KB
  unsigned long long*  packed_ws = (unsigned long long*)(ws + 1314816);   // 512 KB
  int*                 flaglist  = (int*)(ws + 1839104);                  // 256 KB
  unsigned long long*  pairlist  = (unsigned long long*)(ws + 2095360);   // 512 KB
  int*                 counters  = (int*)(ws + 2619648);
  float*               loss_acc  = (float*)(ws + 2619712);

  (void)hipFuncSetAttribute((const void*)k1_main,
        hipFuncAttributeMaxDynamicSharedMemorySize, 45056);
  (void)hipFuncSetAttribute((const void*)k3_out,
        hipFuncAttributeMaxDynamicSharedMemorySize, 65664);

  k0_prep<<<1024, 64, 0, stream>>>(cb, cbT, cnp, counters, loss_acc, idx_ws, packed_ws);
  k1_main<<<1024, 256, 45056, stream>>>(z, cbT, cnp, idx_ws, flaglist, pairlist, counters);
  k2a_quad<<<1024, 256, 0, stream>>>(z, cb, pairlist, counters, idx_ws);
  k2_rescan<<<256, 256, 0, stream>>>(z, cb, flaglist, counters, packed_ws);
  k3_out<<<2048, 256, 65664, stream>>>(z, cb, idx_ws, packed_ws, out, loss_acc);
  k4_loss<<<1, 1, 0, stream>>>(loss_acc, out);
}

// Round 17
// 177.500 us; speedup vs baseline: 1.3786x; 1.3786x over previous
//
#include <hip/hip_runtime.h>
#include <hip/hip_bf16.h>

// VQ-VAE vector quantizer, MI355X. z:(16,512,64,64) f32, codebook:(1024,512) f32.
// d_out f32: z_q (33554432), loss (1), idx (65536).
// R17 = R14 (best: 178us) + prefetch distance 2: 4x16KB ring, stages 0,1 issued
// before the z-prologue (land under it), vmcnt(4) with 8 outstanding.

typedef _Float16 h8 __attribute__((ext_vector_type(8)));
typedef float f32x16 __attribute__((ext_vector_type(16)));

#define OUT_LOSS  33554432
#define OUT_IDX   33554433
#define MARGIN_T  0.15f

__device__ __forceinline__ void gload_lds16(const void* g, void* l) {
  __builtin_amdgcn_global_load_lds(
      (const __attribute__((address_space(1))) void*)g,
      (__attribute__((address_space(3))) void*)l, 16, 0, 0);
}

__device__ __forceinline__ int zswz(int row) {
  return ((row & 3) << 6) | (((row >> 2) & 3) << 4);
}

// ---- K0: cb fp32 -> fp16 FRAGMENT-STREAM cbT + fold-ordered 0.5||c||^2 -------
// cbT byte (c*32+s)*1024 + (hk*32+rr)*16 holds channels [s*16+hk*8,+8) of code
// c*32+rr. Stage (c,h) = contiguous 16KB: coalesced gload_lds in k1.
__global__ __launch_bounds__(64) void k0_prep(
    const float* __restrict__ cb, unsigned short* __restrict__ cbT,
    float* __restrict__ cnp, int* __restrict__ counters, float* __restrict__ loss_acc,
    int* __restrict__ idx_ws, unsigned long long* __restrict__ packed_ws)
{
  const int r = blockIdx.x, l = threadIdx.x;
  const float* row = cb + (size_t)r * 512;
  float4 a  = *(const float4*)(row + l * 8);
  float4 b4 = *(const float4*)(row + l * 8 + 4);
  h8 hv;
  hv[0] = (_Float16)a.x;  hv[1] = (_Float16)a.y;  hv[2] = (_Float16)a.z;  hv[3] = (_Float16)a.w;
  hv[4] = (_Float16)b4.x; hv[5] = (_Float16)b4.y; hv[6] = (_Float16)b4.z; hv[7] = (_Float16)b4.w;
  {
    const int c  = r >> 5, rr = r & 31;
    const int s  = l >> 1;                    // k-slot (16 channels)
    const int hk = l & 1;                     // k-half within slot
    char* dst = reinterpret_cast<char*>(cbT)
              + (size_t)(c * 32 + s) * 1024 + (hk * 32 + rr) * 16;
    *reinterpret_cast<h8*>(dst) = hv;
  }
  float s = a.x*a.x + a.y*a.y + a.z*a.z + a.w*a.w
          + b4.x*b4.x + b4.y*b4.y + b4.z*b4.z + b4.w*b4.w;
  #pragma unroll
  for (int off = 1; off < 64; off <<= 1) s += __shfl_xor(s, off);
  if (l == 0) {
    int jr = r & 31, c = r >> 5;
    int khalf = (jr >> 2) & 1;
    int pat = jr - (khalf << 2);
    int rr2 = (pat & 3) + ((pat >> 3) << 2);
    cnp[(c << 5) + (khalf << 4) + rr2] = 0.5f * s;
  }
  const int pix = (r << 6) + l;                // 1024x64 == 65536
  idx_ws[pix] = (int)0x80000000;
  packed_ws[pix] = ~0ull;
  if (r == 0 && l < 4) counters[l] = 0;
  if (r == 0 && l == 0) *loss_acc = 0.f;
}

// ---- K1: fp16 MFMA scan — 4-ring, prefetch distance 2, coalesced staging -----
// 512 blocks x 256 thr (4 waves), 128 px/block. dynLDS = 4*16384 + 4096 = 69632.
__global__ __launch_bounds__(256, 2) void k1_main(
    const float* __restrict__ z, const unsigned short* __restrict__ cbT,
    const float* __restrict__ cnp,
    int* __restrict__ idx_ws, int* __restrict__ flaglist,
    unsigned long long* __restrict__ pairlist, int* __restrict__ counters)
{
  extern __shared__ char smem[];
  float* cn_lds = reinterpret_cast<float*>(smem + 65536);
  const int tid   = threadIdx.x;
  const int lane  = tid & 63;
  const int wave  = tid >> 6;          // 0..3
  const int pxl   = lane & 31;
  const int khalf = lane >> 5;
  const int px0   = blockIdx.x << 7;   // 128 px/block
  const int b     = px0 >> 12;
  const int hw0   = px0 & 4095;
  const char* cbB = reinterpret_cast<const char*>(cbT);

  // issue stages 0,1 into buf0/buf1 NOW — they land under the z prologue
  #pragma unroll
  for (int i = 0; i < 4; ++i)
    gload_lds16(cbB + tid * 16 + i * 4096, smem + tid * 16 + i * 4096);
  #pragma unroll
  for (int i = 0; i < 4; ++i)
    gload_lds16(cbB + 16384 + tid * 16 + i * 4096, smem + 16384 + tid * 16 + i * 4096);

  // ---- z prologue: 4 passes of [128 px][128 ch] fp16 tile in buf2/buf3 ------
  char* ztile = smem + 32768;
  h8 bfrag[32];
  for (int i = tid; i < 1024; i += 256) cn_lds[i] = cnp[i];
  #pragma unroll
  for (int p = 0; p < 4; ++p) {
    #pragma unroll
    for (int it2 = 0; it2 < 2; ++it2) {
      const int cg  = tid >> 5;                    // 0..7
      const int ch0 = it2 * 64 + cg * 8;
      const int pq  = (tid & 31) * 4;
      const float* src = z + ((size_t)(b * 512 + p * 128 + ch0)) * 4096 + hw0 + pq;
      float4 v[8];
      #pragma unroll
      for (int j = 0; j < 8; ++j) v[j] = *(const float4*)(src + (size_t)j * 4096);
      const float* vf = reinterpret_cast<const float*>(v);
      #pragma unroll
      for (int dp = 0; dp < 4; ++dp) {
        h8 hv;
        #pragma unroll
        for (int j = 0; j < 8; ++j) hv[j] = (_Float16)vf[j * 4 + dp];
        int row = pq + dp;
        int a = (row << 8) + ch0 * 2;
        a ^= zswz(row);
        *reinterpret_cast<h8*>(ztile + a) = hv;
      }
    }
    __syncthreads();
    {
      const int row  = (wave << 5) + pxl;
      const int sw   = zswz(row);
      const int base = (row << 8) + (khalf << 4);
      #pragma unroll
      for (int ss = 0; ss < 8; ++ss)
        bfrag[p * 8 + ss] = *reinterpret_cast<const h8*>(ztile + ((base + (ss << 5)) ^ sw));
    }
    __syncthreads();
  }
  // __syncthreads drained all vmem: vmcnt = 0; stages 0,1 resident in buf0/buf1.

  float v0 = INFINITY, v1 = INFINITY, v2 = INFINITY, v3 = INFINITY;
  int   i0 = 0, i1 = 0, i2 = 0, i3 = 0;
  f32x16 acca, accb;
  #pragma unroll
  for (int i = 0; i < 16; ++i) { acca[i] = 0.f; accb[i] = 0.f; }

  // 4-ring: p0 = stage st (read), staging target for st+2 is p2.
  char* p0 = smem;
  char* p1 = smem + 16384;
  char* p2 = smem + 32768;
  char* p3 = smem + 49152;

  for (int c = 0; c < 32; ++c) {
    // ---- half h=0 (st = 2c): read p0; stage (st+2) -> p2 ----
    {
      const int st = 2 * c;
      if (st < 63) { asm volatile("s_waitcnt vmcnt(4)" ::: "memory"); }
      else         { asm volatile("s_waitcnt vmcnt(0)" ::: "memory"); }
      __builtin_amdgcn_s_barrier();
      __builtin_amdgcn_sched_barrier(0);
      if (st + 2 < 64) {
        const char* src = cbB + (size_t)(st + 2) * 16384 + tid * 16;
        #pragma unroll
        for (int i = 0; i < 4; ++i)
          gload_lds16(src + i * 4096, p2 + tid * 16 + i * 4096);
      }
      const char* ab = p0 + (khalf << 9) + (pxl << 4);
      h8 f[16];
      #pragma unroll
      for (int q = 0; q < 16; ++q) f[q] = *reinterpret_cast<const h8*>(ab + (q << 10));
      __builtin_amdgcn_s_setprio(1);
      #pragma unroll
      for (int q = 0; q < 8; ++q) {
        acca = __builtin_amdgcn_mfma_f32_32x32x16_f16(f[q],     bfrag[q],     acca, 0, 0, 0);
        accb = __builtin_amdgcn_mfma_f32_32x32x16_f16(f[q + 8], bfrag[q + 8], accb, 0, 0, 0);
      }
      __builtin_amdgcn_s_setprio(0);
      char* t = p0; p0 = p1; p1 = p2; p2 = p3; p3 = t;
    }
    // ---- half h=1 (st = 2c+1): read p0; stage (st+2) -> p2 ----
    {
      const int st = 2 * c + 1;
      if (st < 63) { asm volatile("s_waitcnt vmcnt(4)" ::: "memory"); }
      else         { asm volatile("s_waitcnt vmcnt(0)" ::: "memory"); }
      __builtin_amdgcn_s_barrier();
      __builtin_amdgcn_sched_barrier(0);
      if (st + 2 < 64) {
        const char* src = cbB + (size_t)(st + 2) * 16384 + tid * 16;
        #pragma unroll
        for (int i = 0; i < 4; ++i)
          gload_lds16(src + i * 4096, p2 + tid * 16 + i * 4096);
      }
      const char* ab = p0 + (khalf << 9) + (pxl << 4);
      h8 f[16];
      #pragma unroll
      for (int q = 0; q < 16; ++q) f[q] = *reinterpret_cast<const h8*>(ab + (q << 10));
      __builtin_amdgcn_s_setprio(1);
      #pragma unroll
      for (int q = 0; q < 8; ++q) {
        acca = __builtin_amdgcn_mfma_f32_32x32x16_f16(f[q],     bfrag[16 + q], acca, 0, 0, 0);
        accb = __builtin_amdgcn_mfma_f32_32x32x16_f16(f[q + 8], bfrag[24 + q], accb, 0, 0, 0);
      }
      __builtin_amdgcn_s_setprio(0);
      char* t = p0; p0 = p1; p1 = p2; p2 = p3; p3 = t;
    }

    // ---- fold chunk c ----
    {
      const float* cl = cn_lds + (c << 5) + (khalf << 4);
      float4 q0 = *(const float4*)(cl);     float4 q1 = *(const float4*)(cl + 4);
      float4 q2 = *(const float4*)(cl + 8); float4 q3 = *(const float4*)(cl + 12);
      const float cn[16] = {q0.x,q0.y,q0.z,q0.w, q1.x,q1.y,q1.z,q1.w,
                            q2.x,q2.y,q2.z,q2.w, q3.x,q3.y,q3.z,q3.w};
      float sc[16];
      #pragma unroll
      for (int r = 0; r < 16; ++r) sc[r] = cn[r] - (acca[r] + accb[r]);
      float mn = sc[0];
      #pragma unroll
      for (int r = 1; r < 16; ++r) mn = fminf(mn, sc[r]);
      if (__ballot(mn < v3)) {
        const int jbase = (c << 5) + (khalf << 2);
        #pragma unroll
        for (int r = 0; r < 16; ++r) {
          int j = jbase + ((r & 3) + ((r >> 2) << 3));
          float s = sc[r];
          bool c0 = s < v0, c1 = s < v1, c2 = s < v2, c3 = s < v3;
          v3 = c2 ? v2 : (c3 ? s : v3);  i3 = c2 ? i2 : (c3 ? j : i3);
          v2 = c1 ? v1 : (c2 ? s : v2);  i2 = c1 ? i1 : (c2 ? j : i2);
          v1 = c0 ? v0 : (c1 ? s : v1);  i1 = c0 ? i0 : (c1 ? j : i1);
          v0 = c0 ? s  : v0;             i0 = c0 ? j  : i0;
        }
      }
      #pragma unroll
      for (int i = 0; i < 16; ++i) { acca[i] = 0.f; accb[i] = 0.f; }
    }
  }

  // merge khalf halves: snapshot partner's full list BEFORE mutating ours
  {
    float ow0 = __shfl_xor(v0, 32), ow1 = __shfl_xor(v1, 32),
          ow2 = __shfl_xor(v2, 32), ow3 = __shfl_xor(v3, 32);
    int   oj0 = __shfl_xor(i0, 32), oj1 = __shfl_xor(i1, 32),
          oj2 = __shfl_xor(i2, 32), oj3 = __shfl_xor(i3, 32);
    const float ow[4] = {ow0, ow1, ow2, ow3};
    const int   oj[4] = {oj0, oj1, oj2, oj3};
    #pragma unroll
    for (int k = 0; k < 4; ++k) {
      float ov = ow[k]; int oi = oj[k];
      bool c0 = ov < v0, c1 = ov < v1, c2 = ov < v2, c3 = ov < v3;
      v3 = c2 ? v2 : (c3 ? ov : v3);  i3 = c2 ? i2 : (c3 ? oi : i3);
      v2 = c1 ? v1 : (c2 ? ov : v2);  i2 = c1 ? i1 : (c2 ? oi : i2);
      v1 = c0 ? v0 : (c1 ? ov : v1);  i1 = c0 ? i0 : (c1 ? oi : i1);
      v0 = c0 ? ov : v0;              i0 = c0 ? oi : i0;
    }
  }

  const int pix = px0 + (wave << 5) + lane;   // valid for lane<32 only
  bool sane = (v0 == v0) && (v3 == v3) && ((unsigned)i0 < 1024u);
  bool unfl = sane && (v1 - v0 >= MARGIN_T);
  bool quad = sane && !unfl && (v3 - v0 >= MARGIN_T);
  bool qpred = (lane < 32) && quad;
  bool fpred = (lane < 32) && !unfl && !quad;
  if (lane < 32) idx_ws[pix] = unfl ? i0 : (int)0x80000000;

  unsigned long long qm = __ballot(qpred);
  if (qm) {
    int leader = __ffsll(qm) - 1;
    int base = 0;
    if (lane == leader) base = atomicAdd(&counters[1], __popcll(qm));
    base = __shfl(base, leader);
    if (qpred) {
      int pos = __popcll(qm & ((1ull << lane) - 1ull));
      pairlist[base + pos] = (unsigned long long)(unsigned)pix
          | ((unsigned long long)(unsigned)i0 << 16)
          | ((unsigned long long)(unsigned)i1 << 26)
          | ((unsigned long long)(unsigned)i2 << 36)
          | ((unsigned long long)(unsigned)i3 << 46);
    }
  }
  unsigned long long fm = __ballot(fpred);
  if (fm) {
    int leader = __ffsll(fm) - 1;
    int base = 0;
    if (lane == leader) base = atomicAdd(&counters[0], __popcll(fm));
    base = __shfl(base, leader);
    if (fpred) {
      int pos = __popcll(fm & ((1ull << lane) - 1ull));
      flaglist[base + pos] = pix;
    }
  }
}

// ---- K2a: exact fp64 check of <=4 candidates, one wave per pixel --------------
__global__ __launch_bounds__(256) void k2a_quad(
    const float* __restrict__ z, const float* __restrict__ cb,
    const unsigned long long* __restrict__ pairlist, const int* __restrict__ counters,
    int* __restrict__ idx_ws)
{
  const int lane = threadIdx.x & 63;
  const int wid  = (blockIdx.x << 2) + (threadIdx.x >> 6);
  const int nwav = gridDim.x << 2;
  const int nf   = counters[1];
  for (int e = wid; e < nf; e += nwav) {
    unsigned long long pk = pairlist[e];
    int pix = (int)(pk & 0xFFFFull);
    int c0 = (int)((pk >> 16) & 1023ull), c1 = (int)((pk >> 26) & 1023ull);
    int c2 = (int)((pk >> 36) & 1023ull), c3 = (int)((pk >> 46) & 1023ull);
    const float* zp = z + (size_t)(pix >> 12) * 512 * 4096 + (pix & 4095);
    double s0 = 0, s1 = 0, s2 = 0, s3 = 0;
    #pragma unroll
    for (int k = 0; k < 8; ++k) {
      int c = lane + (k << 6);
      double zv2 = 2.0 * (double)zp[(size_t)c * 4096];
      double a;
      a = (double)cb[(size_t)c0 * 512 + c]; s0 = fma(a, a - zv2, s0);
      a = (double)cb[(size_t)c1 * 512 + c]; s1 = fma(a, a - zv2, s1);
      a = (double)cb[(size_t)c2 * 512 + c]; s2 = fma(a, a - zv2, s2);
      a = (double)cb[(size_t)c3 * 512 + c]; s3 = fma(a, a - zv2, s3);
    }
    #pragma unroll
    for (int off = 32; off > 0; off >>= 1) {
      s0 += __shfl_xor(s0, off); s1 += __shfl_xor(s1, off);
      s2 += __shfl_xor(s2, off); s3 += __shfl_xor(s3, off);
    }
    double bv = s0; int bi = c0;
    if (s1 < bv || (s1 == bv && c1 < bi)) { bv = s1; bi = c1; }
    if (s2 < bv || (s2 == bv && c2 < bi)) { bv = s2; bi = c2; }
    if (s3 < bv || (s3 == bv && c3 < bi)) { bv = s3; bi = c3; }
    if (lane == 0) idx_ws[pix] = bi;
  }
}

// ---- K2b: exact fp64 full re-rank (rare: >=4 codes within margin) -------------
__global__ __launch_bounds__(256) void k2_rescan(
    const float* __restrict__ z, const float* __restrict__ cb,
    const int* __restrict__ flaglist, const int* __restrict__ counters,
    unsigned long long* __restrict__ packed_ws)
{
  __shared__ float zb[16][512];
  __shared__ unsigned long long best[16];
  __shared__ int pixl[16];
  const int t = threadIdx.x;
  const int nflag = counters[0];
  const int ntasks = ((nflag + 15) >> 4) << 2;
  for (int task = blockIdx.x; task < ntasks; task += gridDim.x) {
    const int g = task >> 2, q = task & 3;
    int rem = nflag - (g << 4);
    const int npx = rem < 16 ? rem : 16;
    if (t < 16) {
      best[t] = ~0ull;
      pixl[t] = (t < npx) ? flaglist[(g << 4) + t] : 0;
    }
    __syncthreads();
    for (int i = t; i < (npx << 9); i += 256) {
      int p = i >> 9, c = i & 511;
      int pix = pixl[p];
      zb[p][c] = z[((size_t)(pix >> 12) * 512 + c) * 4096 + (pix & 4095)];
    }
    __syncthreads();
    const int j = (q << 8) + t;
    const float* row = cb + (size_t)j * 512;
    double dot[16];
    #pragma unroll
    for (int p = 0; p < 16; ++p) dot[p] = 0.0;
    double cn = 0.0;
    for (int k = 0; k < 512; k += 4) {
      float4 cv = *(const float4*)(row + k);
      double c0 = cv.x, c1 = cv.y, c2 = cv.z, c3 = cv.w;
      cn = fma(c0, c0, cn); cn = fma(c1, c1, cn);
      cn = fma(c2, c2, cn); cn = fma(c3, c3, cn);
      #pragma unroll
      for (int p = 0; p < 16; ++p) {
        dot[p] = fma(c0, (double)zb[p][k + 0], dot[p]);
        dot[p] = fma(c1, (double)zb[p][k + 1], dot[p]);
        dot[p] = fma(c2, (double)zb[p][k + 2], dot[p]);
        dot[p] = fma(c3, (double)zb[p][k + 3], dot[p]);
      }
    }
    #pragma unroll
    for (int p = 0; p < 16; ++p) {
      if (p < npx) {
        double d = fma(-2.0, dot[p], cn);
        unsigned long long u = (unsigned long long)__double_as_longlong(d);
        u = (u >> 63) ? ~u : (u | 0x8000000000000000ull);
        unsigned long long pkk = (u & ~1023ull) | (unsigned long long)j;
        atomicMin(&best[p], pkk);
      }
    }
    __syncthreads();
    if (t < npx) atomicMin(&packed_ws[pixl[t]], best[t]);
    __syncthreads();
  }
}

// ---- K3: gather + transpose-write z_q (f32), idx (f32), loss ------------------
__global__ __launch_bounds__(256) void k3_out(
    const float* __restrict__ z, const float* __restrict__ cb,
    const int* __restrict__ idx_ws, const unsigned long long* __restrict__ packed_ws,
    float* __restrict__ out, float* __restrict__ loss_acc)
{
  extern __shared__ float rows[];
  __shared__ int idxs[32];
  __shared__ float wsum[4];
  const int t = threadIdx.x;
  const int pix0 = blockIdx.x << 5;
  const int b = pix0 >> 12, hw0 = pix0 & 4095;
  if (t < 32) {
    int pix = pix0 + t;
    int v = idx_ws[pix];
    unsigned j = (v < 0) ? (unsigned)(packed_ws[pix] & 1023ull) : (unsigned)v;
    j &= 1023u;
    idxs[t] = (int)j;
    out[OUT_IDX + pix] = (float)j;
  }
  __syncthreads();
  for (int i = t; i < 32 * 128; i += 256) {
    int r = i >> 7, kq = (i & 127) << 2;
    float4 v = *(const float4*)(cb + (size_t)idxs[r] * 512 + kq);
    float* dst = rows + r * 513 + kq;
    dst[0] = v.x; dst[1] = v.y; dst[2] = v.z; dst[3] = v.w;
  }
  __syncthreads();
  const int pl = (t & 7) << 2;
  const int cg = t >> 3;
  float acc = 0.f;
  for (int c0 = 0; c0 < 512; c0 += 32) {
    int c = c0 + cg;
    size_t go = ((size_t)(b * 512 + c)) * 4096 + hw0 + pl;
    float4 zv = *(const float4*)(z + go);
    float q0 = rows[(pl + 0) * 513 + c], q1 = rows[(pl + 1) * 513 + c];
    float q2 = rows[(pl + 2) * 513 + c], q3 = rows[(pl + 3) * 513 + c];
    float d0 = q0 - zv.x, d1 = q1 - zv.y, d2 = q2 - zv.z, d3 = q3 - zv.w;
    acc = fmaf(d0, d0, acc); acc = fmaf(d1, d1, acc);
    acc = fmaf(d2, d2, acc); acc = fmaf(d3, d3, acc);
    float4 qv;
    qv.x = zv.x + d0; qv.y = zv.y + d1;
    qv.z = zv.z + d2; qv.w = zv.w + d3;
    *reinterpret_cast<float4*>(out + go) = qv;
  }
  #pragma unroll
  for (int off = 32; off > 0; off >>= 1) acc += __shfl_down(acc, off);
  if ((t & 63) == 0) wsum[t >> 6] = acc;
  __syncthreads();
  if (t == 0) atomicAdd(loss_acc, wsum[0] + wsum[1] + wsum[2] + wsum[3]);
}

__global__ void k4_loss(const float* __restrict__ loss_acc, float* __restrict__ out)
{
  if (threadIdx.x == 0 && blockIdx.x == 0)
    out[OUT_LOSS] = loss_acc[0] * (1.25f / 33554432.f);
}

// ---- launch --------------------------------------------------------------------
extern "C" void kernel_launch(void* const* d_in, const int* in_sizes, int n_in,
                              void* d_out, int out_size, void* d_ws, size_t ws_size,
                              hipStream_t stream) {
  const float* z  = (const float*)d_in[0];
  const float* cb = (const float*)d_in[1];
  float* out = (float*)d_out;
  char* ws = (char*)d_ws;
  unsigned short*      cbT       = (unsigned short*)(ws);                 // 1 MB
  float*               cnp       = (float*)(ws + 1048576);                // 4 KB
  int*                 idx_ws    = (int*)(ws + 1052672);                  // 256 KB
  unsigned long long*  packed_ws = (unsigned long long*)(ws + 1314816);   // 512 KB
  int*                 flaglist  = (int*)(ws + 1839104);                  // 256 KB
  unsigned long long*  pairlist  = (unsigned long long*)(ws + 2095360);   // 512 KB
  int*                 counters  = (int*)(ws + 2619648);
  float*               loss_acc  = (float*)(ws + 2619712);

  (void)hipFuncSetAttribute((const void*)k1_main,
        hipFuncAttributeMaxDynamicSharedMemorySize, 69632);
  (void)hipFuncSetAttribute((const void*)k3_out,
        hipFuncAttributeMaxDynamicSharedMemorySize, 65664);

  k0_prep<<<1024, 64, 0, stream>>>(cb, cbT, cnp, counters, loss_acc, idx_ws, packed_ws);
  k1_main<<<512, 256, 69632, stream>>>(z, cbT, cnp, idx_ws, flaglist, pairlist, counters);
  k2a_quad<<<1024, 256, 0, stream>>>(z, cb, pairlist, counters, idx_ws);
  k2_rescan<<<256, 256, 0, stream>>>(z, cb, flaglist, counters, packed_ws);
  k3_out<<<2048, 256, 65664, stream>>>(z, cb, idx_ws, packed_ws, out, loss_acc);
  k4_loss<<<1, 1, 0, stream>>>(loss_acc, out);
}